// Round 14
// baseline (286.344 us; speedup 1.0000x reference)
//
#include <hip/hip_runtime.h>

#define N_NODES 100000
#define N_EDGES 1600000
#define D 128
#define SLOT_CAP 64
#define TILE 32            // nodes per tile; 100000 = 3125 * 32
#define NTILE 3125
#define NSLICE 8           // feature column slices == XCDs (16 cols each)
#define SLICE_U32 800000   // u32 per slice: 100000 nodes * 8

// fused_pre geometry (round-6/11 known-good)
#define NR           8
#define RANGE_N      (N_NODES / NR)      // 12500
#define CHUNK4       512                 // int4 per chunk = 2048 edges
#define NCHUNK       ((N_EDGES / 4 + CHUNK4 - 1) / CHUNK4)   // 782
#define FILL_BLOCKS  (NR * NCHUNK)       // 6256
#define FEAT4        (N_NODES * D / 4)   // 3,200,000 float4
#define CONVF_BASE   FILL_BLOCKS
#define CONVF_BLOCKS 12500
#define CONVW_BASE   (CONVF_BASE + CONVF_BLOCKS)
#define TOTAL_BLOCKS (CONVW_BASE + 16)

typedef __attribute__((ext_vector_type(8))) short bf16x8;
typedef __attribute__((ext_vector_type(4))) float f32x4;
typedef __attribute__((ext_vector_type(4))) float evf4;
typedef __attribute__((ext_vector_type(2))) unsigned int evu2;

static __device__ __forceinline__ evf4 nt_load_f4(const void* p) {
    return __builtin_nontemporal_load((const evf4*)p);
}
static __device__ __forceinline__ void nt_store_u2(void* p, evu2 v) {
    __builtin_nontemporal_store(v, (evu2*)p);
}

static __device__ __forceinline__ unsigned int f2bf(float f) {
    union { float f; unsigned int u; } v; v.f = f;
    return (v.u + 0x7FFFu + ((v.u >> 16) & 1u)) >> 16;   // RNE
}
static __device__ __forceinline__ float bflo(unsigned int u) {
    return __uint_as_float(u << 16);
}
static __device__ __forceinline__ float bfhi(unsigned int u) {
    return __uint_as_float(u & 0xFFFF0000u);
}

// ---------------------------------------------------------------------------
// Fused pre-pass (round-6/11 fill, conv -> SLICED bf16 layout).
//   fill blocks [0, FILL_BLOCKS): XCD-range-partitioned per-node slot fill.
//   conv-F: feature f32 -> fbf_s[slice][node][16 cols] bf16 (nt stores).
//   conv-W: W f32 -> Wbf row-major bf16.
// Slot entry: (src << 15) | trunc(w * 32768).
// ---------------------------------------------------------------------------
__global__ __launch_bounds__(256) void fused_pre(const float* __restrict__ feat,
                                                 const float* __restrict__ W,
                                                 unsigned int* __restrict__ fbf_s,
                                                 unsigned int* __restrict__ Wbf2,
                                                 const int* __restrict__ src,
                                                 const int4* __restrict__ dst4,
                                                 const float* __restrict__ w,
                                                 int* __restrict__ cnt,
                                                 int* __restrict__ slots) {
    const int b = blockIdx.x;
    const int tid = threadIdx.x;

    if (b < FILL_BLOCKS) {
        const unsigned r = b & (NR - 1);
        const int chunk = b >> 3;
        const unsigned rlo = r * RANGE_N;
        const int base4 = chunk * CHUNK4;

#pragma unroll
        for (int j = 0; j < 2; ++j) {
            int i4 = base4 + j * 256 + tid;
            if (i4 < N_EDGES / 4) {
                int4 dd = dst4[i4];
#define PROCE(K, dc)                                                          \
                if ((unsigned)((dc) - rlo) < (unsigned)RANGE_N) {             \
                    int   sc = src[i4 * 4 + (K)];                             \
                    float wc = w[i4 * 4 + (K)];                               \
                    int p = atomicAdd(&cnt[dc], 1);                           \
                    if (p < SLOT_CAP)                                         \
                        slots[(dc) * SLOT_CAP + p] =                          \
                            (sc << 15) | (int)(wc * 32768.0f);                \
                }
                PROCE(0, dd.x)
                PROCE(1, dd.y)
                PROCE(2, dd.z)
                PROCE(3, dd.w)
#undef PROCE
            }
        }
        return;
    }

    if (b < CONVW_BASE) {                         // feature -> sliced bf16
        int i = (b - CONVF_BASE) * 256 + tid;
        if (i < FEAT4) {
            evf4 v = nt_load_f4(feat + i * 4);
            evu2 o;
            o.x = f2bf(v.x) | (f2bf(v.y) << 16);
            o.y = f2bf(v.z) | (f2bf(v.w) << 16);
            int n = i >> 5, c4 = i & 31;
            int s = c4 >> 2, sub = (c4 & 3) * 2;  // slice, u32 offset in node's 8
            // evu2 index: (s*800000 + n*8 + sub) / 2
            nt_store_u2((evu2*)fbf_s + (s * (SLICE_U32 / 2) + n * 4 + (sub >> 1)), o);
        }
        return;
    }

    {                                             // W -> bf16 (4096 float4)
        int i = (b - CONVW_BASE) * 256 + tid;
        if (i < 4096) {
            evf4 v = nt_load_f4(W + i * 4);
            evu2 o;
            o.x = f2bf(v.x) | (f2bf(v.y) << 16);
            o.y = f2bf(v.z) | (f2bf(v.w) << 16);
            nt_store_u2((evu2*)Wbf2 + i, o);
        }
    }
}

// ---------------------------------------------------------------------------
// Sliced gather: block (tile t, slice x), blockIdx = t*8 + x. Round-robin
// dispatch pins slice x to XCD x; slice (3.2 MB) is L2-RESIDENT -> random
// per-edge 32 B reads are L2 hits. 8 lanes per edge (4 B each), 8 edges per
// wave-load, depth-2 pipeline, shfl_xor(8/16/32) column reduce.
// Output: h slice -> hbuf[node][128] bf16 (dense row-major, u32-packed).
// ---------------------------------------------------------------------------
__global__ __launch_bounds__(256) void gather_slices(const int* __restrict__ cnt,
                                                     const int* __restrict__ slots,
                                                     const unsigned int* __restrict__ fbf_s,
                                                     unsigned int* __restrict__ hbuf) {
    const int tid  = threadIdx.x;
    const int wave = tid >> 6;
    const int lane = tid & 63;
    const int t = blockIdx.x >> 3;
    const int x = blockIdx.x & 7;
    const int g8 = lane >> 3;                  // edge group 0..7
    const int sl = lane & 7;                   // col-pair 0..7 within slice
    const unsigned int* fs = fbf_s + x * SLICE_U32;

    for (int n = 0; n < 8; ++n) {
        const int row = wave * 8 + n;
        const int v = t * TILE + row;
        int c = cnt[v];
        c = c < SLOT_CAP ? c : SLOT_CAP;
        int ent = (lane < c) ? slots[v * SLOT_CAP + lane] : 0;

        float a0 = 0.f, a1 = 0.f;

#define FETCH(U, W, I)                                                        \
        {   int pe = __shfl(ent, (I) + g8);                                   \
            W = (float)(pe & 32767) * (1.0f / 32768.0f);                      \
            int s = ((unsigned)pe) >> 15;                                     \
            U = fs[s * 8 + sl]; }

        if (c > 0) {
            const int c16 = (c + 15) & ~15;    // pad to x16 (dummies: w=0)
            unsigned u0, u1;
            float w0, w1;
            FETCH(u0, w0, 0) FETCH(u1, w1, 8)
            for (int i = 0; i < c16; i += 16) {
                a0 += w0 * bflo(u0); a1 += w0 * bfhi(u0);
                if (i + 16 < c16) FETCH(u0, w0, i + 16)
                a0 += w1 * bflo(u1); a1 += w1 * bfhi(u1);
                if (i + 24 < c16) FETCH(u1, w1, i + 24)
            }
        }
#undef FETCH

        a0 += __shfl_xor(a0, 8);  a1 += __shfl_xor(a1, 8);
        a0 += __shfl_xor(a0, 16); a1 += __shfl_xor(a1, 16);
        a0 += __shfl_xor(a0, 32); a1 += __shfl_xor(a1, 32);

        if (lane < 8)
            hbuf[v * 64 + x * 8 + sl] = f2bf(a0) | (f2bf(a1) << 16);
    }
}

// ---------------------------------------------------------------------------
// GEMM + bias per 32-node tile: stage hbuf tile into XOR-swizzled LDS, then
// round-6 MFMA phases (16x16x32 bf16), bias, coalesced f32 store.
// ---------------------------------------------------------------------------
__global__ __launch_bounds__(256) void gemm_bias(const unsigned int* __restrict__ hbuf,
                                                 const unsigned short* __restrict__ Wbf,
                                                 const float* __restrict__ bias,
                                                 float* __restrict__ y) {
    __shared__ char smem[16384];               // h (8 KB swizzled); C (16 KB) overlays
    char*  hT = smem;
    float* C  = (float*)smem;

    const int tid   = threadIdx.x;
    const int wave  = tid >> 6;
    const int lane  = tid & 63;
    const int vbase = blockIdx.x * TILE;

    // stage: 512 uint4 (32 rows x 16), swizzle byte ^= (row&7)<<4
    const uint4* h4 = (const uint4*)hbuf + (long long)vbase * 16;
#pragma unroll
    for (int k = 0; k < 2; ++k) {
        int idx = k * 256 + tid;
        int row = idx >> 4, c16 = idx & 15;
        uint4 vv = h4[idx];
        *(uint4*)(hT + row * 256 + ((c16 * 16) ^ ((row & 7) << 4))) = vv;
    }
    __syncthreads();

    // MFMA phase (round-6 P2)
    const int m0  = (wave & 1) * 16;
    const int n0  = (wave >> 1) * 64;
    const int lr  = lane & 15;
    const int lkb = (lane >> 4) * 16;
    const int lk  = (lane >> 4) * 8;
    const int arow = m0 + lr;

    bf16x8 a[4];
#pragma unroll
    for (int t = 0; t < 4; ++t) {
        int cb = (t * 64 + lkb) ^ ((arow & 7) << 4);
        a[t] = *(const bf16x8*)(hT + arow * 256 + cb);
    }
    __syncthreads();                           // frags in regs; smem reusable as C

    f32x4 acc2[4];
#pragma unroll
    for (int ni = 0; ni < 4; ++ni) acc2[ni] = (f32x4){0.f, 0.f, 0.f, 0.f};
#pragma unroll
    for (int t = 0; t < 4; ++t) {
#pragma unroll
        for (int ni = 0; ni < 4; ++ni) {
            bf16x8 b = *(const bf16x8*)(Wbf + (n0 + ni * 16 + lr) * D + t * 32 + lk);
            acc2[ni] = __builtin_amdgcn_mfma_f32_16x16x32_bf16(a[t], b, acc2[ni], 0, 0, 0);
        }
    }

    // bias + C stage + coalesced store (round-6 P3)
#pragma unroll
    for (int ni = 0; ni < 4; ++ni) {
        float bv = bias[n0 + ni * 16 + lr];
#pragma unroll
        for (int r = 0; r < 4; ++r) {
            int row = m0 + (lane >> 4) * 4 + r;
            C[row * D + n0 + ni * 16 + lr] = acc2[ni][r] + bv;
        }
    }
    __syncthreads();

    float4* y4 = (float4*)(y + (long long)vbase * D);
    const float4* C4 = (const float4*)C;
#pragma unroll
    for (int rep = 0; rep < 4; ++rep)
        y4[rep * 256 + tid] = C4[rep * 256 + tid];
}

extern "C" void kernel_launch(void* const* d_in, const int* in_sizes, int n_in,
                              void* d_out, int out_size, void* d_ws, size_t ws_size,
                              hipStream_t stream) {
    const float* feature = (const float*)d_in[0];
    const int*   src     = (const int*)d_in[1];
    const int*   dst     = (const int*)d_in[2];
    const float* ew      = (const float*)d_in[3];
    const float* W       = (const float*)d_in[4];
    const float* b       = (const float*)d_in[5];
    float* y = (float*)d_out;

    char* ws = (char*)d_ws;
    unsigned int*   fbf_s = (unsigned int*)(ws);                  // 25,600,000 B (sliced)
    int*            cnt   = (int*)(ws + 25600000);                //    400,000 B
    int*            slots = (int*)(ws + 26000000);                // 25,600,000 B
    unsigned int*   hbuf  = (unsigned int*)(ws + 51600000);       // 25,600,000 B
    unsigned short* Wbf   = (unsigned short*)(ws + 77200000);     //     32,768 B

    hipMemsetAsync(cnt, 0, 400000, stream);

    fused_pre<<<TOTAL_BLOCKS, 256, 0, stream>>>(
        feature, W,
        fbf_s, (unsigned int*)Wbf,
        src, (const int4*)dst, ew,
        cnt, slots);

    gather_slices<<<NTILE * NSLICE, 256, 0, stream>>>(cnt, slots, fbf_s, hbuf);

    gemm_bias<<<NTILE, 256, 0, stream>>>(hbuf, (const unsigned short*)Wbf, b, y);
}

// Round 15
// 194.559 us; speedup vs baseline: 1.4718x; 1.4718x over previous
//
#include <hip/hip_runtime.h>

#define N_NODES 100000
#define N_EDGES 1600000
#define D 128
#define SLOT_CAP 64
#define TILE 32            // nodes per gather block (100000 = 3125 * 32)

#define NR        8                    // node ranges == XCDs
#define RANGE_N   (N_NODES / NR)       // 12500
#define RMAGIC    343598u              // ceil(2^32 / 12500)
#define CHUNK     2048                 // edges per pass-1 block
#define NCHUNK    ((N_EDGES + CHUNK - 1) / CHUNK)   // 782
#define SEG_W     128                  // per-(range,chunk,wave) capacity (mean 64)
#define P2K       98                   // pass-2 blocks per range (784 total)
#define SUB       2                    // fill2 sub-range passes
#define SUBN      (RANGE_N / SUB)      // 6250 nodes -> 1.6 MB slot set, L2-fits

#define FEAT4        (N_NODES * D / 4) // 3,200,000 float4 -> uint2
#define CONVF_BASE   NCHUNK
#define CONVF_BLOCKS 12500
#define CONVW_BASE   (CONVF_BASE + CONVF_BLOCKS)
#define TOTAL_BLOCKS (CONVW_BASE + 16)

typedef __attribute__((ext_vector_type(8))) short bf16x8;
typedef __attribute__((ext_vector_type(4))) float f32x4;
typedef __attribute__((ext_vector_type(4))) float evf4;
typedef __attribute__((ext_vector_type(2))) unsigned int evu2;

static __device__ __forceinline__ evf4 nt_load_f4(const void* p) {
    return __builtin_nontemporal_load((const evf4*)p);
}
static __device__ __forceinline__ void nt_store_u2(void* p, evu2 v) {
    __builtin_nontemporal_store(v, (evu2*)p);
}

static __device__ __forceinline__ unsigned int f2bf(float f) {
    union { float f; unsigned int u; } v; v.f = f;
    return (v.u + 0x7FFFu + ((v.u >> 16) & 1u)) >> 16;   // RNE
}
static __device__ __forceinline__ float bflo(unsigned int u) {
    return __uint_as_float(u << 16);
}
static __device__ __forceinline__ float bfhi(unsigned int u) {
    return __uint_as_float(u & 0xFFFF0000u);
}

// ---------------------------------------------------------------------------
// Pass 1 (+conv): single scan of the edge list; route edges into 8 node-range
// partitions. Per-wave LDS cursors (32 total) -> 4x less LDS-atomic
// serialization; sequential 8B segment writes -> write-combining.
//   entry: x = dlo (node within range), y = (src<<15) | trunc(w*32768)
//          (y is the final slot word -> fill2 is pure move)
// ---------------------------------------------------------------------------
__global__ __launch_bounds__(256) void pre1(const float* __restrict__ feat,
                                            const float* __restrict__ W,
                                            unsigned int* __restrict__ fbf2,
                                            unsigned int* __restrict__ Wbf2,
                                            const int4* __restrict__ src4,
                                            const int4* __restrict__ dst4,
                                            const float4* __restrict__ w4,
                                            int2* __restrict__ part,
                                            int* __restrict__ partcnt) {
    const int b = blockIdx.x;
    const int tid = threadIdx.x;

    if (b < NCHUNK) {
        __shared__ int lcur[4][NR];
        if (tid < 32) lcur[tid >> 3][tid & 7] = 0;
        __syncthreads();

        const int wave = tid >> 6;
        const int base4 = b * (CHUNK / 4);
#pragma unroll
        for (int j = 0; j < 2; ++j) {
            int i4 = base4 + j * 256 + tid;
            if (i4 < N_EDGES / 4) {
                int4   dd = dst4[i4];
                int4   ss = src4[i4];
                float4 ww = w4[i4];
#define ROUTE(dc, sc, wc)                                                     \
                {   unsigned r = __umulhi((unsigned)(dc), RMAGIC);            \
                    int dlo = (dc) - (int)(r * RANGE_N);                      \
                    int sw = ((sc) << 15) | (int)((wc) * 32768.0f);           \
                    int pos = atomicAdd(&lcur[wave][r], 1);                   \
                    if (pos < SEG_W)                                          \
                        part[(long long)((r * NCHUNK + b) * 4 + wave) *       \
                             SEG_W + pos] = make_int2(dlo, sw);               \
                }
                ROUTE(dd.x, ss.x, ww.x)
                ROUTE(dd.y, ss.y, ww.y)
                ROUTE(dd.z, ss.z, ww.z)
                ROUTE(dd.w, ss.w, ww.w)
#undef ROUTE
            }
        }
        __syncthreads();
        if (tid < 32) {
            int w2 = tid >> 3, r2 = tid & 7;
            int c = lcur[w2][r2];
            partcnt[(r2 * NCHUNK + b) * 4 + w2] = c < SEG_W ? c : SEG_W;
        }
        return;
    }

    if (b < CONVW_BASE) {                         // feature -> bf16 (nt)
        int i = (b - CONVF_BASE) * 256 + tid;
        if (i < FEAT4) {
            evf4 v = nt_load_f4(feat + i * 4);
            evu2 o;
            o.x = f2bf(v.x) | (f2bf(v.y) << 16);
            o.y = f2bf(v.z) | (f2bf(v.w) << 16);
            nt_store_u2(fbf2 + i * 2, o);
        }
        return;
    }

    {                                             // W -> bf16 (4096 float4)
        int i = (b - CONVW_BASE) * 256 + tid;
        if (i < 4096) {
            evf4 v = nt_load_f4(W + i * 4);
            evu2 o;
            o.x = f2bf(v.x) | (f2bf(v.y) << 16);
            o.y = f2bf(v.z) | (f2bf(v.w) << 16);
            nt_store_u2(Wbf2 + i * 2, o);
        }
    }
}

// ---------------------------------------------------------------------------
// Pass 2: per-range slot fill in SUB sub-range passes. Block b serves range
// b&7 (round-robin -> one XCD per range). Per sub-pass working set:
// partition 1.6 MB + slots 1.6 MB (6250 nodes) + cnt 12.5 KB < 4 MB L2 ->
// slot lines stay resident across all ~16 writes -> writeback ~1 line/node.
// ---------------------------------------------------------------------------
__global__ __launch_bounds__(256) void fill2(const int2* __restrict__ part,
                                             const int* __restrict__ partcnt,
                                             int* __restrict__ cnt,
                                             int* __restrict__ slots) {
    const int r = blockIdx.x & (NR - 1);
    const int k = blockIdx.x >> 3;
    const int rbase = r * RANGE_N;

    for (int sub = 0; sub < SUB; ++sub) {
        const unsigned lo = sub * SUBN;
        for (int c = k; c < NCHUNK; c += P2K) {
            const int segbase = (r * NCHUNK + c) * 4;
#pragma unroll
            for (int half = 0; half < 2; ++half) {
                int idx = half * 256 + threadIdx.x;   // 0..511 over 4 segs x 128
                int w2 = idx >> 7, pos = idx & (SEG_W - 1);
                int n = partcnt[segbase + w2];
                if (pos < n) {
                    int2 e = part[(long long)(segbase + w2) * SEG_W + pos];
                    if ((unsigned)e.x - lo < (unsigned)SUBN) {
                        int dst = rbase + e.x;
                        int p = atomicAdd(&cnt[dst], 1);
                        if (p < SLOT_CAP) slots[dst * SLOT_CAP + p] = e.y;
                    }
                }
            }
        }
    }
}

// ---------------------------------------------------------------------------
// Fused gather + GEMM per 32-node tile, 4 waves (round-6 known-good, 88.8us).
// Phase 1: depth-4 pipelined gather (quarter-wave g owns edge i+g).
// Phase 2: 16x16x32 bf16 MFMA, A from XOR-swizzled LDS h-tile, B from global.
// Phase 3: C+bias staged in LDS, coalesced float4 store.
// ---------------------------------------------------------------------------
__global__ __launch_bounds__(256) void gather_gemm(const int* __restrict__ cnt,
                                                   const int* __restrict__ slots,
                                                   const unsigned short* __restrict__ fbf,
                                                   const unsigned short* __restrict__ Wbf,
                                                   const float* __restrict__ bias,
                                                   float* __restrict__ y) {
    __shared__ char smem[TILE * D * 4];        // 16 KB: h (8 KB bf16) then C (16 KB f32)
    char*  hT = smem;
    float* C  = (float*)smem;

    const int tid   = threadIdx.x;
    const int wave  = tid >> 6;
    const int lane  = tid & 63;
    const int vbase = blockIdx.x * TILE;
    const int g  = lane >> 4;                  // quarter-wave group 0..3
    const int ql = lane & 15;
    const uint4* fbf4 = (const uint4*)fbf;     // 16 uint4 per 128-col row

    // ---- Phase 1: gather h rows ----
    for (int n = 0; n < 8; ++n) {
        const int row = wave * 8 + n;
        const int v = vbase + row;
        int c = cnt[v];
        c = c < SLOT_CAP ? c : SLOT_CAP;
        int ent = (lane < c) ? slots[v * SLOT_CAP + lane] : 0;

        float acc[8];
#pragma unroll
        for (int j = 0; j < 8; ++j) acc[j] = 0.f;

#define FETCH(P, W, I)                                                        \
        {   int pe = __shfl(ent, (I) + g);                                    \
            W = (float)(pe & 32767) * (1.0f / 32768.0f);                      \
            int s = ((unsigned)pe) >> 15;                                     \
            P = fbf4[(long long)s * 16 + ql]; }
#define PROC(P, W)                                                            \
        {   acc[0] += W * bflo(P.x); acc[1] += W * bfhi(P.x);                 \
            acc[2] += W * bflo(P.y); acc[3] += W * bfhi(P.y);                 \
            acc[4] += W * bflo(P.z); acc[5] += W * bfhi(P.z);                 \
            acc[6] += W * bflo(P.w); acc[7] += W * bfhi(P.w); }

        if (c > 0) {
            const int c16 = (c + 15) & ~15;    // pad to x16 (dummies: w=0, row 0)
            uint4 p0, p1, p2, p3;
            float w0, w1, w2, w3;
            FETCH(p0, w0, 0) FETCH(p1, w1, 4) FETCH(p2, w2, 8) FETCH(p3, w3, 12)
            for (int i = 0; i < c16; i += 16) {
                PROC(p0, w0) if (i + 16 < c16) FETCH(p0, w0, i + 16)
                PROC(p1, w1) if (i + 20 < c16) FETCH(p1, w1, i + 20)
                PROC(p2, w2) if (i + 24 < c16) FETCH(p2, w2, i + 24)
                PROC(p3, w3) if (i + 28 < c16) FETCH(p3, w3, i + 28)
            }
        }
#undef FETCH
#undef PROC

#pragma unroll
        for (int j = 0; j < 8; ++j) {
            acc[j] += __shfl_xor(acc[j], 16);
            acc[j] += __shfl_xor(acc[j], 32);
        }
        if (lane < 16) {
            uint4 pk;
            pk.x = f2bf(acc[0]) | (f2bf(acc[1]) << 16);
            pk.y = f2bf(acc[2]) | (f2bf(acc[3]) << 16);
            pk.z = f2bf(acc[4]) | (f2bf(acc[5]) << 16);
            pk.w = f2bf(acc[6]) | (f2bf(acc[7]) << 16);
            int cb = (lane * 16) ^ ((row & 7) << 4);
            *(uint4*)(hT + row * 256 + cb) = pk;
        }
    }
    __syncthreads();

    // ---- Phase 2: load A-frags from LDS, then MFMA with B from global ----
    const int m0  = (wave & 1) * 16;
    const int n0  = (wave >> 1) * 64;
    const int lr  = lane & 15;
    const int lkb = (lane >> 4) * 16;          // k byte offset within 256B row
    const int lk  = (lane >> 4) * 8;           // k element offset
    const int arow = m0 + lr;

    bf16x8 a[4];
#pragma unroll
    for (int t = 0; t < 4; ++t) {
        int cb = (t * 64 + lkb) ^ ((arow & 7) << 4);
        a[t] = *(const bf16x8*)(hT + arow * 256 + cb);
    }
    __syncthreads();                           // frags in regs; smem now reusable as C

    f32x4 acc2[4];
#pragma unroll
    for (int ni = 0; ni < 4; ++ni) acc2[ni] = (f32x4){0.f, 0.f, 0.f, 0.f};
#pragma unroll
    for (int t = 0; t < 4; ++t) {
#pragma unroll
        for (int ni = 0; ni < 4; ++ni) {
            bf16x8 b = *(const bf16x8*)(Wbf + (n0 + ni * 16 + lr) * D + t * 32 + lk);
            acc2[ni] = __builtin_amdgcn_mfma_f32_16x16x32_bf16(a[t], b, acc2[ni], 0, 0, 0);
        }
    }

    // ---- Phase 3: C+bias -> LDS, coalesced store ----
#pragma unroll
    for (int ni = 0; ni < 4; ++ni) {
        float bv = bias[n0 + ni * 16 + lr];
#pragma unroll
        for (int r = 0; r < 4; ++r) {
            int row = m0 + (lane >> 4) * 4 + r;
            C[row * D + n0 + ni * 16 + lr] = acc2[ni][r] + bv;
        }
    }
    __syncthreads();

    float4* y4 = (float4*)(y + (long long)vbase * D);
    const float4* C4 = (const float4*)C;
#pragma unroll
    for (int rep = 0; rep < 4; ++rep)
        y4[rep * 256 + tid] = C4[rep * 256 + tid];
}

extern "C" void kernel_launch(void* const* d_in, const int* in_sizes, int n_in,
                              void* d_out, int out_size, void* d_ws, size_t ws_size,
                              hipStream_t stream) {
    const float* feature = (const float*)d_in[0];
    const int*   src     = (const int*)d_in[1];
    const int*   dst     = (const int*)d_in[2];
    const float* ew      = (const float*)d_in[3];
    const float* W       = (const float*)d_in[4];
    const float* b       = (const float*)d_in[5];
    float* y = (float*)d_out;

    char* ws = (char*)d_ws;
    unsigned short* fbf     = (unsigned short*)(ws);              // 25,600,000 B
    int*            cnt     = (int*)(ws + 25600000);              //    400,000 B
    int*            slots   = (int*)(ws + 26000000);              // 25,600,000 B
    unsigned short* Wbf     = (unsigned short*)(ws + 51600000);   //     32,768 B
    int2*           part    = (int2*)(ws + 51640000);             // 25,624,576 B
    int*            partcnt = (int*)(ws + 77264576);              //    100,096 B

    hipMemsetAsync(cnt, 0, 400000, stream);

    pre1<<<TOTAL_BLOCKS, 256, 0, stream>>>(
        feature, W,
        (unsigned int*)fbf, (unsigned int*)Wbf,
        (const int4*)src, (const int4*)dst, (const float4*)ew,
        part, partcnt);

    fill2<<<NR * P2K, 256, 0, stream>>>(part, partcnt, cnt, slots);

    gather_gemm<<<N_NODES / TILE, 256, 0, stream>>>(cnt, slots, fbf, Wbf, b, y);
}

// Round 16
// 143.880 us; speedup vs baseline: 1.9902x; 1.3522x over previous
//
#include <hip/hip_runtime.h>

#define N_NODES 100000
#define N_EDGES 1600000
#define D 128
#define SLOT_CAP 64
#define TILE 32            // nodes per gather block; 100000 = 3125 * 32
#define NSUP 391           // supertiles of 256 nodes (last partial: 160)
#define SEGCAP 4608        // per-supertile segment cap (mean 4096, +8 sigma)

#define CHUNK  2048        // edges per fill block
#define NCHUNK 782
#define FEAT4        (N_NODES * D / 4)   // 3,200,000 float4
#define CONVF_BASE   NCHUNK
#define CONVF_BLOCKS 12500
#define CONVW_BASE   (CONVF_BASE + CONVF_BLOCKS)
#define TOTAL_BLOCKS (CONVW_BASE + 16)

typedef __attribute__((ext_vector_type(8))) short bf16x8;
typedef __attribute__((ext_vector_type(4))) float f32x4;
typedef __attribute__((ext_vector_type(4))) float evf4;
typedef __attribute__((ext_vector_type(2))) unsigned int evu2;

static __device__ __forceinline__ evf4 nt_load_f4(const void* p) {
    return __builtin_nontemporal_load((const evf4*)p);
}
static __device__ __forceinline__ void nt_store_u2(void* p, evu2 v) {
    __builtin_nontemporal_store(v, (evu2*)p);
}

static __device__ __forceinline__ unsigned int f2bf(float f) {
    union { float f; unsigned int u; } v; v.f = f;
    return (v.u + 0x7FFFu + ((v.u >> 16) & 1u)) >> 16;   // RNE
}
static __device__ __forceinline__ float bflo(unsigned int u) {
    return __uint_as_float(u << 16);
}
static __device__ __forceinline__ float bfhi(unsigned int u) {
    return __uint_as_float(u & 0xFFFF0000u);
}

// ---------------------------------------------------------------------------
// Pre-pass: single edge scan + conv, one dispatch.
//   fill blocks [0, NCHUNK): each handles 2048 edges.
//     A: LDS histogram over 391 supertiles.
//     B: ONE global atomicAdd per (block, supertile) -> dense base reserve.
//        (782 increments/cursor total -- far below contention threshold.)
//     C: write 8B entries {dst, (src<<15)|w15} at base+local. Per-wave
//        same-line stores coalesce (runs are contiguous); open tail lines
//        (391 x 64B) stay L2-resident -> write-combining, no line RMW.
//   conv-F blocks: feature f32 -> bf16 (nt).  conv-W: W f32 -> bf16.
// ---------------------------------------------------------------------------
__global__ __launch_bounds__(256) void pre1(const float* __restrict__ feat,
                                            const float* __restrict__ W,
                                            unsigned int* __restrict__ fbf2,
                                            unsigned int* __restrict__ Wbf2,
                                            const int4* __restrict__ src4,
                                            const int4* __restrict__ dst4,
                                            const float4* __restrict__ w4,
                                            int* __restrict__ scur,
                                            int2* __restrict__ staged) {
    const int b = blockIdx.x;
    const int tid = threadIdx.x;

    if (b < NCHUNK) {
        __shared__ int hist[NSUP];
        __shared__ int base[NSUP];

        for (int i = tid; i < NSUP; i += 256) hist[i] = 0;
        __syncthreads();

        int2 ent[8];
        int  sup[8];
        const int base4 = b * (CHUNK / 4);
#pragma unroll
        for (int j = 0; j < 2; ++j) {
            int i4 = base4 + j * 256 + tid;
            bool ok = i4 < N_EDGES / 4;
            int4   dd = ok ? dst4[i4] : make_int4(0, 0, 0, 0);
            int4   ss = ok ? src4[i4] : make_int4(0, 0, 0, 0);
            float4 ww = ok ? w4[i4]   : make_float4(0.f, 0.f, 0.f, 0.f);
#define COLLECT(K, dc, sc, wc)                                                \
            {   int k = j * 4 + (K);                                          \
                if (ok) {                                                     \
                    int wq = (int)((wc) * 32768.0f);                          \
                    ent[k] = make_int2((dc), ((sc) << 15) | wq);              \
                    sup[k] = (dc) >> 8;                                       \
                    atomicAdd(&hist[sup[k]], 1);                              \
                } else sup[k] = -1;                                           \
            }
            COLLECT(0, dd.x, ss.x, ww.x)
            COLLECT(1, dd.y, ss.y, ww.y)
            COLLECT(2, dd.z, ss.z, ww.z)
            COLLECT(3, dd.w, ss.w, ww.w)
#undef COLLECT
        }
        __syncthreads();

        for (int i = tid; i < NSUP; i += 256) {
            int c = hist[i];
            base[i] = c ? atomicAdd(&scur[i], c) : 0;
        }
        __syncthreads();
        for (int i = tid; i < NSUP; i += 256) hist[i] = 0;
        __syncthreads();

#pragma unroll
        for (int k = 0; k < 8; ++k) {
            if (sup[k] >= 0) {
                int lo = atomicAdd(&hist[sup[k]], 1);
                int pos = base[sup[k]] + lo;
                if (pos < SEGCAP) staged[sup[k] * SEGCAP + pos] = ent[k];
            }
        }
        return;
    }

    if (b < CONVW_BASE) {                         // feature -> bf16 (nt)
        int i = (b - CONVF_BASE) * 256 + tid;
        if (i < FEAT4) {
            evf4 v = nt_load_f4(feat + i * 4);
            evu2 o;
            o.x = f2bf(v.x) | (f2bf(v.y) << 16);
            o.y = f2bf(v.z) | (f2bf(v.w) << 16);
            nt_store_u2(fbf2 + i * 2, o);
        }
        return;
    }

    {                                             // W -> bf16 (4096 float4)
        int i = (b - CONVW_BASE) * 256 + tid;
        if (i < 4096) {
            evf4 v = nt_load_f4(W + i * 4);
            evu2 o;
            o.x = f2bf(v.x) | (f2bf(v.y) << 16);
            o.y = f2bf(v.z) | (f2bf(v.w) << 16);
            nt_store_u2(Wbf2 + i * 2, o);
        }
    }
}

// ---------------------------------------------------------------------------
// Fused bin + gather + GEMM. Grid permuted so all 8 tile-blocks of supertile
// s run on XCD s%8 (q%8 == s%8) -> segment read is L2-hit for 7 of 8.
// P0: scan supertile segment, filter own tile, LDS-bin by node (round-13).
// P1: depth-4 pipelined gather per row, entries from LDS bins (round-6).
// P2: 16x16x32 bf16 MFMA, A from XOR-swizzled LDS h-tile, B from global.
// P3: C+bias staged in LDS, coalesced float4 store.
// ---------------------------------------------------------------------------
__global__ __launch_bounds__(256) void gather_gemm(const int* __restrict__ scur,
                                                   const int2* __restrict__ staged,
                                                   const unsigned short* __restrict__ fbf,
                                                   const unsigned short* __restrict__ Wbf,
                                                   const float* __restrict__ bias,
                                                   float* __restrict__ y) {
    // q -> (s, j) with q%8 == s%8
    const int q = blockIdx.x;
    const int m = q & 7;
    const int rest = q >> 3;          // 0..391
    const int j = rest & 7;
    const int i2 = rest >> 3;         // 0..48
    const int s = m + 8 * i2;
    if (s >= NSUP) return;
    const int tile = s * 8 + j;
    if (tile >= N_NODES / TILE) return;

    __shared__ int  scnt[TILE];
    __shared__ char smem[16384];               // [bins 8K | h 8K]; C (16K) overlays
    int*   bins = (int*)smem;                  // [32][64]
    char*  hT   = smem + 8192;                 // [32] rows x 256 B, XOR-swizzled
    float* C    = (float*)smem;

    const int tid   = threadIdx.x;
    const int wave  = tid >> 6;
    const int lane  = tid & 63;
    const int vbase = tile * TILE;
    const int g  = lane >> 4;                  // quarter-wave group 0..3
    const int ql = lane & 15;
    const uint4* fbf4 = (const uint4*)fbf;     // 16 uint4 per 128-col row

    // ---- P0: bin this tile's entries from the supertile segment ----
    if (tid < TILE) scnt[tid] = 0;
    __syncthreads();
    {
        int nb = scur[s];
        nb = nb < SEGCAP ? nb : SEGCAP;
        const int2* sp = staged + s * SEGCAP;
        for (int i = tid; i < nb; i += 256) {
            int2 e = sp[i];
            if ((e.x >> 5) == tile) {
                int rr = e.x & 31;
                int pos = atomicAdd(&scnt[rr], 1);
                if (pos < SLOT_CAP) bins[rr * SLOT_CAP + pos] = e.y;
            }
        }
    }
    __syncthreads();

    // ---- P1: gather h rows (depth-4 pipeline, entries from LDS) ----
    for (int n = 0; n < 8; ++n) {
        const int row = wave * 8 + n;
        int c = scnt[row];
        c = c < SLOT_CAP ? c : SLOT_CAP;
        int ent = (lane < c) ? bins[row * SLOT_CAP + lane] : 0;

        float acc[8];
#pragma unroll
        for (int jj = 0; jj < 8; ++jj) acc[jj] = 0.f;

#define FETCH(P, W, I)                                                        \
        {   int pe = __shfl(ent, (I) + g);                                    \
            W = (float)(pe & 32767) * (1.0f / 32768.0f);                      \
            int sv = ((unsigned)pe) >> 15;                                    \
            P = fbf4[(long long)sv * 16 + ql]; }
#define PROC(P, W)                                                            \
        {   acc[0] += W * bflo(P.x); acc[1] += W * bfhi(P.x);                 \
            acc[2] += W * bflo(P.y); acc[3] += W * bfhi(P.y);                 \
            acc[4] += W * bflo(P.z); acc[5] += W * bfhi(P.z);                 \
            acc[6] += W * bflo(P.w); acc[7] += W * bfhi(P.w); }

        if (c > 0) {
            const int c16 = (c + 15) & ~15;    // pad to x16 (dummies: w=0, row 0)
            uint4 p0, p1, p2, p3;
            float w0, w1, w2, w3;
            FETCH(p0, w0, 0) FETCH(p1, w1, 4) FETCH(p2, w2, 8) FETCH(p3, w3, 12)
            for (int i = 0; i < c16; i += 16) {
                PROC(p0, w0) if (i + 16 < c16) FETCH(p0, w0, i + 16)
                PROC(p1, w1) if (i + 20 < c16) FETCH(p1, w1, i + 20)
                PROC(p2, w2) if (i + 24 < c16) FETCH(p2, w2, i + 24)
                PROC(p3, w3) if (i + 28 < c16) FETCH(p3, w3, i + 28)
            }
        }
#undef FETCH
#undef PROC

#pragma unroll
        for (int jj = 0; jj < 8; ++jj) {
            acc[jj] += __shfl_xor(acc[jj], 16);
            acc[jj] += __shfl_xor(acc[jj], 32);
        }
        if (lane < 16) {
            uint4 pk;
            pk.x = f2bf(acc[0]) | (f2bf(acc[1]) << 16);
            pk.y = f2bf(acc[2]) | (f2bf(acc[3]) << 16);
            pk.z = f2bf(acc[4]) | (f2bf(acc[5]) << 16);
            pk.w = f2bf(acc[6]) | (f2bf(acc[7]) << 16);
            int cb = (lane * 16) ^ ((row & 7) << 4);
            *(uint4*)(hT + row * 256 + cb) = pk;
        }
    }
    __syncthreads();

    // ---- P2: load A-frags from LDS, then MFMA with B from global ----
    const int m0  = (wave & 1) * 16;
    const int n0  = (wave >> 1) * 64;
    const int lr  = lane & 15;
    const int lkb = (lane >> 4) * 16;          // k byte offset within 256B row
    const int lk  = (lane >> 4) * 8;           // k element offset
    const int arow = m0 + lr;

    bf16x8 a[4];
#pragma unroll
    for (int t = 0; t < 4; ++t) {
        int cb = (t * 64 + lkb) ^ ((arow & 7) << 4);
        a[t] = *(const bf16x8*)(hT + arow * 256 + cb);
    }
    __syncthreads();                           // frags in regs; smem reusable as C

    f32x4 acc2[4];
#pragma unroll
    for (int ni = 0; ni < 4; ++ni) acc2[ni] = (f32x4){0.f, 0.f, 0.f, 0.f};
#pragma unroll
    for (int t = 0; t < 4; ++t) {
#pragma unroll
        for (int ni = 0; ni < 4; ++ni) {
            bf16x8 bb = *(const bf16x8*)(Wbf + (n0 + ni * 16 + lr) * D + t * 32 + lk);
            acc2[ni] = __builtin_amdgcn_mfma_f32_16x16x32_bf16(a[t], bb, acc2[ni], 0, 0, 0);
        }
    }

    // ---- P3: C+bias -> LDS, coalesced store ----
#pragma unroll
    for (int ni = 0; ni < 4; ++ni) {
        float bv = bias[n0 + ni * 16 + lr];
#pragma unroll
        for (int r = 0; r < 4; ++r) {
            int row = m0 + (lane >> 4) * 4 + r;
            C[row * D + n0 + ni * 16 + lr] = acc2[ni][r] + bv;
        }
    }
    __syncthreads();

    float4* y4 = (float4*)(y + (long long)vbase * D);
    const float4* C4 = (const float4*)C;
#pragma unroll
    for (int rep = 0; rep < 4; ++rep)
        y4[rep * 256 + tid] = C4[rep * 256 + tid];
}

extern "C" void kernel_launch(void* const* d_in, const int* in_sizes, int n_in,
                              void* d_out, int out_size, void* d_ws, size_t ws_size,
                              hipStream_t stream) {
    const float* feature = (const float*)d_in[0];
    const int*   src     = (const int*)d_in[1];
    const int*   dst     = (const int*)d_in[2];
    const float* ew      = (const float*)d_in[3];
    const float* W       = (const float*)d_in[4];
    const float* b       = (const float*)d_in[5];
    float* y = (float*)d_out;

    char* ws = (char*)d_ws;
    unsigned short* fbf    = (unsigned short*)(ws);               // 25,600,000 B
    unsigned short* Wbf    = (unsigned short*)(ws + 25600000);    //     32,768 B
    int*            scur   = (int*)(ws + 25632768);               //      1,564 B
    int2*           staged = (int2*)(ws + 25634432);              // 14,413,824 B

    hipMemsetAsync(scur, 0, 1564, stream);

    pre1<<<TOTAL_BLOCKS, 256, 0, stream>>>(
        feature, W,
        (unsigned int*)fbf, (unsigned int*)Wbf,
        (const int4*)src, (const int4*)dst, (const float4*)ew,
        scur, staged);

    gather_gemm<<<8 * 8 * 49, 256, 0, stream>>>(scur, staged, fbf, Wbf, b, y);
}

// Round 17
// 133.414 us; speedup vs baseline: 2.1463x; 1.0784x over previous
//
#include <hip/hip_runtime.h>

#define N_NODES 100000
#define N_EDGES 1600000
#define D 128
#define SLOT_CAP 64
#define TILE 32            // nodes per gather block; 100000 = 3125 * 32
#define NSUP 391           // supertiles of 256 nodes
#define NSUPP 512          // padded
#define SEGCAP 4608        // per-supertile segment cap (mean 4096, +8 sigma)

#define CHUNK  2048        // edges per fill block
#define NCHUNK 782
#define FEAT4        (N_NODES * D / 4)   // 3,200,000 float4
#define CONVF_BASE   NCHUNK
#define CONVF_BLOCKS 12500
#define CONVW_BASE   (CONVF_BASE + CONVF_BLOCKS)
#define TOTAL_BLOCKS (CONVW_BASE + 16)

typedef __attribute__((ext_vector_type(8))) short bf16x8;
typedef __attribute__((ext_vector_type(4))) float f32x4;
typedef __attribute__((ext_vector_type(4))) float evf4;
typedef __attribute__((ext_vector_type(2))) unsigned int evu2;

static __device__ __forceinline__ evf4 nt_load_f4(const void* p) {
    return __builtin_nontemporal_load((const evf4*)p);
}
static __device__ __forceinline__ void nt_store_u2(void* p, evu2 v) {
    __builtin_nontemporal_store(v, (evu2*)p);
}

static __device__ __forceinline__ unsigned int f2bf(float f) {
    union { float f; unsigned int u; } v; v.f = f;
    return (v.u + 0x7FFFu + ((v.u >> 16) & 1u)) >> 16;   // RNE
}
static __device__ __forceinline__ float bflo(unsigned int u) {
    return __uint_as_float(u << 16);
}
static __device__ __forceinline__ float bfhi(unsigned int u) {
    return __uint_as_float(u & 0xFFFF0000u);
}

// ---------------------------------------------------------------------------
// Pre-pass: single edge scan + conv, one dispatch.
//   fill blocks [0, NCHUNK): 2048 edges each.
//     A: LDS histogram over supertiles (dst>>8).
//     B: prefix-scan -> local offsets; ONE global atomicAdd per (block,sup)
//        reserves a dense run in the supertile segment.
//     C: LDS counting-sort entries by sup (16 KB sortbuf), then stream out:
//        consecutive lanes write consecutive addresses of the same run ->
//        line-merged bursts, no cross-XCD tail ping.
//   conv-F blocks: feature f32 -> bf16 (nt).  conv-W: W f32 -> bf16.
// Entry: {x = dst, y = (src<<15)|trunc(w*32768)}.
// ---------------------------------------------------------------------------
__global__ __launch_bounds__(256) void pre1(const float* __restrict__ feat,
                                            const float* __restrict__ W,
                                            unsigned int* __restrict__ fbf2,
                                            unsigned int* __restrict__ Wbf2,
                                            const int4* __restrict__ src4,
                                            const int4* __restrict__ dst4,
                                            const float4* __restrict__ w4,
                                            int* __restrict__ scur,
                                            int2* __restrict__ staged) {
    const int b = blockIdx.x;
    const int tid = threadIdx.x;

    if (b < NCHUNK) {
        __shared__ int  hist[NSUPP];
        __shared__ int  loff[NSUPP];
        __shared__ int  place[NSUPP];
        __shared__ int  obase[NSUPP];
        __shared__ int  ps[256];
        __shared__ int2 sortbuf[CHUNK];

        for (int i = tid; i < NSUPP; i += 256) { hist[i] = 0; place[i] = 0; }
        __syncthreads();

        int2 ent[8];
        int  sup[8];
        const int base4 = b * (CHUNK / 4);
#pragma unroll
        for (int j = 0; j < 2; ++j) {
            int i4 = base4 + j * 256 + tid;
            bool ok = i4 < N_EDGES / 4;
            int4   dd = ok ? dst4[i4] : make_int4(0, 0, 0, 0);
            int4   ss = ok ? src4[i4] : make_int4(0, 0, 0, 0);
            float4 ww = ok ? w4[i4]   : make_float4(0.f, 0.f, 0.f, 0.f);
#define COLLECT(K, dc, sc, wc)                                                \
            {   int k = j * 4 + (K);                                          \
                if (ok) {                                                     \
                    int wq = (int)((wc) * 32768.0f);                          \
                    ent[k] = make_int2((dc), ((sc) << 15) | wq);              \
                    sup[k] = (dc) >> 8;                                       \
                    atomicAdd(&hist[sup[k]], 1);                              \
                } else sup[k] = -1;                                           \
            }
            COLLECT(0, dd.x, ss.x, ww.x)
            COLLECT(1, dd.y, ss.y, ww.y)
            COLLECT(2, dd.z, ss.z, ww.z)
            COLLECT(3, dd.w, ss.w, ww.w)
#undef COLLECT
        }
        __syncthreads();

        // prefix scan over 512 padded sups (pairs per thread)
        int h0 = hist[2 * tid], h1 = hist[2 * tid + 1];
        int pv = h0 + h1;
        ps[tid] = pv;
        __syncthreads();
        for (int off = 1; off < 256; off <<= 1) {
            int t2 = (tid >= off) ? ps[tid - off] : 0;
            __syncthreads();
            ps[tid] += t2;
            __syncthreads();
        }
        int excl = ps[tid] - pv;
        loff[2 * tid]     = excl;
        loff[2 * tid + 1] = excl + h0;
        const int total = ps[255];

        // global reserve per sup
        for (int i = tid; i < NSUP; i += 256) {
            int c = hist[i];
            obase[i] = c ? atomicAdd(&scur[i], c) : 0;
        }
        __syncthreads();

        // place into sortbuf (counting sort by sup)
#pragma unroll
        for (int k = 0; k < 8; ++k) {
            if (sup[k] >= 0) {
                int lo = atomicAdd(&place[sup[k]], 1);
                sortbuf[loff[sup[k]] + lo] = ent[k];
            }
        }
        __syncthreads();

        // stream out: consecutive lanes -> consecutive addresses per run
        for (int i = tid; i < total; i += 256) {
            int2 e = sortbuf[i];
            int s = e.x >> 8;
            int pos = obase[s] + (i - loff[s]);
            if (pos < SEGCAP) staged[s * SEGCAP + pos] = e;
        }
        return;
    }

    if (b < CONVW_BASE) {                         // feature -> bf16 (nt)
        int i = (b - CONVF_BASE) * 256 + tid;
        if (i < FEAT4) {
            evf4 v = nt_load_f4(feat + i * 4);
            evu2 o;
            o.x = f2bf(v.x) | (f2bf(v.y) << 16);
            o.y = f2bf(v.z) | (f2bf(v.w) << 16);
            nt_store_u2(fbf2 + i * 2, o);
        }
        return;
    }

    {                                             // W -> bf16 (4096 float4)
        int i = (b - CONVW_BASE) * 256 + tid;
        if (i < 4096) {
            evf4 v = nt_load_f4(W + i * 4);
            evu2 o;
            o.x = f2bf(v.x) | (f2bf(v.y) << 16);
            o.y = f2bf(v.z) | (f2bf(v.w) << 16);
            nt_store_u2(Wbf2 + i * 2, o);
        }
    }
}

// ---------------------------------------------------------------------------
// Fused bin + gather + GEMM (round-16 proven). Grid permuted: q%8 == s%8 so
// all 8 tile-blocks of supertile s share an XCD (segment reads L2-hit).
// P0: scan supertile segment (int4 = 2 entries/lane), filter own tile,
//     LDS-bin by node.
// P1: depth-4 pipelined gather per row, entries from LDS bins.
// P2: 16x16x32 bf16 MFMA, A from XOR-swizzled LDS h-tile, B from global.
// P3: C+bias staged in LDS, coalesced float4 store.
// ---------------------------------------------------------------------------
__global__ __launch_bounds__(256) void gather_gemm(const int* __restrict__ scur,
                                                   const int2* __restrict__ staged,
                                                   const unsigned short* __restrict__ fbf,
                                                   const unsigned short* __restrict__ Wbf,
                                                   const float* __restrict__ bias,
                                                   float* __restrict__ y) {
    const int q = blockIdx.x;
    const int m = q & 7;
    const int rest = q >> 3;
    const int j = rest & 7;
    const int i2 = rest >> 3;
    const int s = m + 8 * i2;
    if (s >= NSUP) return;
    const int tile = s * 8 + j;
    if (tile >= N_NODES / TILE) return;

    __shared__ int  scnt[TILE];
    __shared__ char smem[16384];               // [bins 8K | h 8K]; C (16K) overlays
    int*   bins = (int*)smem;                  // [32][64]
    char*  hT   = smem + 8192;                 // [32] rows x 256 B, XOR-swizzled
    float* C    = (float*)smem;

    const int tid   = threadIdx.x;
    const int wave  = tid >> 6;
    const int lane  = tid & 63;
    const int vbase = tile * TILE;
    const int g  = lane >> 4;
    const int ql = lane & 15;
    const uint4* fbf4 = (const uint4*)fbf;

    // ---- P0: bin this tile's entries from the supertile segment ----
    if (tid < TILE) scnt[tid] = 0;
    __syncthreads();
    {
        int nb = scur[s];
        nb = nb < SEGCAP ? nb : SEGCAP;
        const int4* sp2 = (const int4*)(staged + s * SEGCAP);
        int npair = (nb + 1) >> 1;
        for (int i = tid; i < npair; i += 256) {
            int4 ee = sp2[i];
            if ((ee.x >> 5) == tile) {
                int pos = atomicAdd(&scnt[ee.x & 31], 1);
                if (pos < SLOT_CAP) bins[(ee.x & 31) * SLOT_CAP + pos] = ee.y;
            }
            int k2 = 2 * i + 1;
            if (k2 < nb && (ee.z >> 5) == tile) {
                int pos = atomicAdd(&scnt[ee.z & 31], 1);
                if (pos < SLOT_CAP) bins[(ee.z & 31) * SLOT_CAP + pos] = ee.w;
            }
        }
    }
    __syncthreads();

    // ---- P1: gather h rows (depth-4 pipeline, entries from LDS) ----
    for (int n = 0; n < 8; ++n) {
        const int row = wave * 8 + n;
        int c = scnt[row];
        c = c < SLOT_CAP ? c : SLOT_CAP;
        int ent = (lane < c) ? bins[row * SLOT_CAP + lane] : 0;

        float acc[8];
#pragma unroll
        for (int jj = 0; jj < 8; ++jj) acc[jj] = 0.f;

#define FETCH(P, W, I)                                                        \
        {   int pe = __shfl(ent, (I) + g);                                    \
            W = (float)(pe & 32767) * (1.0f / 32768.0f);                      \
            int sv = ((unsigned)pe) >> 15;                                    \
            P = fbf4[(long long)sv * 16 + ql]; }
#define PROC(P, W)                                                            \
        {   acc[0] += W * bflo(P.x); acc[1] += W * bfhi(P.x);                 \
            acc[2] += W * bflo(P.y); acc[3] += W * bfhi(P.y);                 \
            acc[4] += W * bflo(P.z); acc[5] += W * bfhi(P.z);                 \
            acc[6] += W * bflo(P.w); acc[7] += W * bfhi(P.w); }

        if (c > 0) {
            const int c16 = (c + 15) & ~15;
            uint4 p0, p1, p2, p3;
            float w0, w1, w2, w3;
            FETCH(p0, w0, 0) FETCH(p1, w1, 4) FETCH(p2, w2, 8) FETCH(p3, w3, 12)
            for (int i = 0; i < c16; i += 16) {
                PROC(p0, w0) if (i + 16 < c16) FETCH(p0, w0, i + 16)
                PROC(p1, w1) if (i + 20 < c16) FETCH(p1, w1, i + 20)
                PROC(p2, w2) if (i + 24 < c16) FETCH(p2, w2, i + 24)
                PROC(p3, w3) if (i + 28 < c16) FETCH(p3, w3, i + 28)
            }
        }
#undef FETCH
#undef PROC

#pragma unroll
        for (int jj = 0; jj < 8; ++jj) {
            acc[jj] += __shfl_xor(acc[jj], 16);
            acc[jj] += __shfl_xor(acc[jj], 32);
        }
        if (lane < 16) {
            uint4 pk;
            pk.x = f2bf(acc[0]) | (f2bf(acc[1]) << 16);
            pk.y = f2bf(acc[2]) | (f2bf(acc[3]) << 16);
            pk.z = f2bf(acc[4]) | (f2bf(acc[5]) << 16);
            pk.w = f2bf(acc[6]) | (f2bf(acc[7]) << 16);
            int cb = (lane * 16) ^ ((row & 7) << 4);
            *(uint4*)(hT + row * 256 + cb) = pk;
        }
    }
    __syncthreads();

    // ---- P2: load A-frags from LDS, then MFMA with B from global ----
    const int m0  = (wave & 1) * 16;
    const int n0  = (wave >> 1) * 64;
    const int lr  = lane & 15;
    const int lkb = (lane >> 4) * 16;
    const int lk  = (lane >> 4) * 8;
    const int arow = m0 + lr;

    bf16x8 a[4];
#pragma unroll
    for (int t = 0; t < 4; ++t) {
        int cb = (t * 64 + lkb) ^ ((arow & 7) << 4);
        a[t] = *(const bf16x8*)(hT + arow * 256 + cb);
    }
    __syncthreads();

    f32x4 acc2[4];
#pragma unroll
    for (int ni = 0; ni < 4; ++ni) acc2[ni] = (f32x4){0.f, 0.f, 0.f, 0.f};
#pragma unroll
    for (int t = 0; t < 4; ++t) {
#pragma unroll
        for (int ni = 0; ni < 4; ++ni) {
            bf16x8 bb = *(const bf16x8*)(Wbf + (n0 + ni * 16 + lr) * D + t * 32 + lk);
            acc2[ni] = __builtin_amdgcn_mfma_f32_16x16x32_bf16(a[t], bb, acc2[ni], 0, 0, 0);
        }
    }

    // ---- P3: C+bias -> LDS, coalesced store ----
#pragma unroll
    for (int ni = 0; ni < 4; ++ni) {
        float bv = bias[n0 + ni * 16 + lr];
#pragma unroll
        for (int r = 0; r < 4; ++r) {
            int row = m0 + (lane >> 4) * 4 + r;
            C[row * D + n0 + ni * 16 + lr] = acc2[ni][r] + bv;
        }
    }
    __syncthreads();

    float4* y4 = (float4*)(y + (long long)vbase * D);
    const float4* C4 = (const float4*)C;
#pragma unroll
    for (int rep = 0; rep < 4; ++rep)
        y4[rep * 256 + tid] = C4[rep * 256 + tid];
}

extern "C" void kernel_launch(void* const* d_in, const int* in_sizes, int n_in,
                              void* d_out, int out_size, void* d_ws, size_t ws_size,
                              hipStream_t stream) {
    const float* feature = (const float*)d_in[0];
    const int*   src     = (const int*)d_in[1];
    const int*   dst     = (const int*)d_in[2];
    const float* ew      = (const float*)d_in[3];
    const float* W       = (const float*)d_in[4];
    const float* b       = (const float*)d_in[5];
    float* y = (float*)d_out;

    char* ws = (char*)d_ws;
    unsigned short* fbf    = (unsigned short*)(ws);               // 25,600,000 B
    unsigned short* Wbf    = (unsigned short*)(ws + 25600000);    //     32,768 B
    int*            scur   = (int*)(ws + 25632768);               //      1,564 B
    int2*           staged = (int2*)(ws + 25634432);              // 14,413,824 B

    hipMemsetAsync(scur, 0, 1564, stream);

    pre1<<<TOTAL_BLOCKS, 256, 0, stream>>>(
        feature, W,
        (unsigned int*)fbf, (unsigned int*)Wbf,
        (const int4*)src, (const int4*)dst, (const float4*)ew,
        scur, staged);

    gather_gemm<<<8 * 8 * 49, 256, 0, stream>>>(scur, staged, fbf, Wbf, b, y);
}